// Round 2
// baseline (6712.068 us; speedup 1.0000x reference)
//
#include <hip/hip_runtime.h>
#include <math.h>

typedef _Float16 f16;
typedef f16  f16x8 __attribute__((ext_vector_type(8)));
typedef f16  f16x4 __attribute__((ext_vector_type(4)));
typedef float f32x4 __attribute__((ext_vector_type(4)));

#define NB 64
#define NC 16
#define NF 128
#define ND 256
#define NSTEP 60
#define GRID_ELEMS (NB*64*64*NC)   // 16 MB fp32
#define NPIX (NB*64*64)

#define KCONV 160                  // 9 taps * 16ch padded to 10 taps
#define HSS   136                  // hs row stride (f16) — proven conflict-balanced

// weight buffer layout (f16 elements) inside d_out scratch region
#define OFF_CW 0             // [128][160]
#define OFF_W1 20480         // [256][128]
#define OFF_W2 53248         // [16][256]

// ---------------- init: grid ch0 = input, others 0 ----------------
__global__ void init_grid(const float* __restrict__ inp, float* __restrict__ g) {
    int i = blockIdx.x * 256 + threadIdx.x;
    if (i >= GRID_ELEMS) return;
    int c = i & 15;
    g[i] = (c == 0) ? inp[i >> 4] : 0.0f;
}

// ---------------- prep: f16 transposed weights ----------------
__global__ void prep_weights(const float* __restrict__ cw, const float* __restrict__ w1,
                             const float* __restrict__ w2, f16* __restrict__ wb) {
    int i = blockIdx.x * 256 + threadIdx.x;   // 57344 threads exactly
    float v; int off, idx;
    if (i < 20480) {                          // cwT[f][k], k = tap*16+c (tap9 zero)
        int f = i / 160, k = i - f * 160;
        v = (k < 144) ? cw[k * 128 + f] : 0.0f;
        off = OFF_CW; idx = i;
    } else if (i < 20480 + 32768) {           // w1T[j][f]
        int r = i - 20480;
        int j = r >> 7, f = r & 127;
        v = w1[f * 256 + j];
        off = OFF_W1; idx = r;
    } else {                                  // w2T[c][j]
        int r = i - 20480 - 32768;
        int c = r >> 8, j = r & 255;
        v = w2[j * 16 + c];
        off = OFF_W2; idx = r;
    }
    wb[off + idx] = (f16)v;
}

// ---------------- fused NCA step (pure-f16 MFMA, fp32 accumulate/state) ----------------
// R16: PIXEL-SPLIT waves. 16x8 px tile, 4 waves; wave w owns pixel rows {2w,2w+1}
// and computes ALL filters / ALL j for them:
//   - conv B-reads and dense1 hB-reads drop 4x (no wave redundancy on LDS)
//   - wave holds the complete j-sum -> dense2 ends in registers: redF, the
//     cross-wave reduction, the tail phase and 2 barriers are DELETED
//   - single __syncthreads (after halo staging); waves free-run
//   - LDS 40576 B -> 4 blocks/CU; launch_bounds(256,4) caps VGPR 128
// conv/dense1 chains bit-identical to R15; dense2/final fp32 sums reassociated only.
__global__ __launch_bounds__(256, 4) void nca_step(
    const float* __restrict__ gin, float* __restrict__ gout,
    const f16* __restrict__ wb,
    const float* __restrict__ cb, const float* __restrict__ b1, const float* __restrict__ b2)
{
    // hs [128 px][HSS] = 34816 B ; halo [10*18][16] = 5760 B ; total 40576 B
    __shared__ f16 smem[20288];
    f16* const hs   = smem;                  // 17408 elems
    f16* const halo = smem + 17408;          // [(hy*18+hx)]*16 + c

    const int t    = threadIdx.x;
    const int w    = t >> 6;
    const int lane = t & 63;
    const int q    = lane >> 4;
    const int l16  = lane & 15;

    // XCD swizzle: d = xcd + 8*(tl + 32*ip) -> image b = xcd*8 + ip, tile tl
    const int d  = blockIdx.x;
    const int kk = d >> 3;
    const int b  = ((d & 7) << 3) | (kk >> 5);
    const int tl = kk & 31;
    const int y0 = (tl >> 2) << 3;           // 8 row-bands of 8 rows
    const int x0 = (tl & 3) << 4;            // 4 col-bands of 16 cols

    const float* gb  = gin  + (size_t)b * 64 * 64 * 16;
    float*       gob = gout + (size_t)b * 64 * 64 * 16;

    // ---- stage halo (f16), zero-pad SAME; f32x4 global reads ----
    for (int i = t; i < 720; i += 256) {     // 180 cells x 4 c-quads
        int c4 = (i & 3) << 2;
        int xy = i >> 2;
        int xx = xy % 18;                    // 0..17
        int yy = xy / 18;                    // 0..9
        int gy = y0 + yy - 1, gx = x0 + xx - 1;
        f32x4 v = {0.f, 0.f, 0.f, 0.f};
        if ((unsigned)gy < 64u && (unsigned)gx < 64u)
            v = *(const f32x4*)(gb + (gy * 64 + gx) * 16 + c4);
        f16x4 hv;
        hv.x = (f16)v.x; hv.y = (f16)v.y; hv.z = (f16)v.z; hv.w = (f16)v.w;
        *(f16x4*)(halo + xy * 16 + c4) = hv;
    }
    __syncthreads();                         // the ONLY block-wide barrier

    const int pr = w << 1;                   // wave's first pixel row

    // ================= conv 3x3x16 -> 128 (wave: 2 rows, ALL filters) =================
    f32x4 acc[8][2];
    #pragma unroll
    for (int ft = 0; ft < 8; ++ft) {
        f32x4 bias = *(const f32x4*)(cb + ft * 16 + q * 4);
        acc[ft][0] = bias;
        acc[ft][1] = bias;
    }

    #pragma unroll
    for (int kc = 0; kc < 5; ++kc) {
        // cA streamed per kc (8 fragments live, not 40); identical addresses
        // across waves/blocks -> L1-served
        f16x8 cA[8];
        #pragma unroll
        for (int ft = 0; ft < 8; ++ft)
            cA[ft] = *(const f16x8*)(wb + OFF_CW +
                (size_t)(ft * 16 + l16) * KCONV + kc * 32 + q * 8);
        int tap = kc * 2 + (q >> 1);
        if (tap > 8) tap = 8;                // k>=144: weights are zero
        int dy = tap / 3, dx = tap - dy * 3;
        #pragma unroll
        for (int pp = 0; pp < 2; ++pp) {
            int hy = pr + pp + dy;
            int hx = l16 + dx;
            f16x8 bf = *(const f16x8*)(halo + (hy * 18 + hx) * 16 + (q & 1) * 8);
            #pragma unroll
            for (int ft = 0; ft < 8; ++ft)
                acc[ft][pp] = __builtin_amdgcn_mfma_f32_16x16x32_f16(cA[ft], bf, acc[ft][pp], 0, 0, 0);
        }
    }

    // relu in fp32, pack f16, write own rows of hs (b64)
    #pragma unroll
    for (int pp = 0; pp < 2; ++pp)
        #pragma unroll
        for (int ft = 0; ft < 8; ++ft) {
            f32x4 a = acc[ft][pp];
            f16x4 pk;
            pk.x = (f16)fmaxf(a.x, 0.0f);
            pk.y = (f16)fmaxf(a.y, 0.0f);
            pk.z = (f16)fmaxf(a.z, 0.0f);
            pk.w = (f16)fmaxf(a.w, 0.0f);
            *(f16x4*)(hs + ((pr + pp) * 16 + l16) * HSS + ft * 16 + q * 4) = pk;
        }
    // no barrier: this wave reads back only its own rows (lgkmcnt ordering suffices)

    // ============ dense1 (128->256, relu) fused w/ dense2 (256->16) ============
    f16x8 hB[2][4];
    #pragma unroll
    for (int pp = 0; pp < 2; ++pp)
        #pragma unroll
        for (int kc = 0; kc < 4; ++kc)
            hB[pp][kc] = *(const f16x8*)(hs + ((pr + pp) * 16 + l16) * HSS + kc * 32 + q * 8);

    // early residual-state loads: hide HBM latency under the dense math
    float gv[2][4], a0v[2][4];
    #pragma unroll
    for (int pp = 0; pp < 2; ++pp)
        #pragma unroll
        for (int r = 0; r < 4; ++r) {
            const int y = y0 + pr + pp;
            const int x = x0 + q * 4 + r;
            const size_t pixb = ((size_t)y * 64 + x) * 16;
            a0v[pp][r] = gb[pixb];           // exact fp32 ch0 (alive flag)
            gv[pp][r]  = gb[pixb + l16];
        }
    const float b2v = b2[l16];

    f32x4 daccA[2], daccB[2];                // even/odd-jt partials (ILP)
    #pragma unroll
    for (int pp = 0; pp < 2; ++pp) {
        daccA[pp].x = 0.f; daccA[pp].y = 0.f; daccA[pp].z = 0.f; daccA[pp].w = 0.f;
        daccB[pp].x = 0.f; daccB[pp].y = 0.f; daccB[pp].z = 0.f; daccB[pp].w = 0.f;
    }

    auto dense_jt = [&](int jt, f32x4* dst) {
        f32x4 b1v = *(const f32x4*)(b1 + jt * 16 + q * 4);
        f16x4 w2f = *(const f16x4*)(wb + OFF_W2 + (size_t)l16 * 256 + jt * 16 + q * 4);
        f16x8 dAk[4];
        #pragma unroll
        for (int kc = 0; kc < 4; ++kc)
            dAk[kc] = *(const f16x8*)(wb + OFF_W1 +
                (size_t)(jt * 16 + l16) * 128 + kc * 32 + q * 8);
        #pragma unroll
        for (int pp = 0; pp < 2; ++pp) {
            f32x4 a1 = b1v;
            #pragma unroll
            for (int kc = 0; kc < 4; ++kc)
                a1 = __builtin_amdgcn_mfma_f32_16x16x32_f16(dAk[kc], hB[pp][kc], a1, 0, 0, 0);
            f16x4 pk;
            pk.x = (f16)fmaxf(a1.x, 0.0f);
            pk.y = (f16)fmaxf(a1.y, 0.0f);
            pk.z = (f16)fmaxf(a1.z, 0.0f);
            pk.w = (f16)fmaxf(a1.w, 0.0f);
            // dense1 D (row=j,col=x) IS the K=16 A-fragment (m=x,k=j)
            dst[pp] = __builtin_amdgcn_mfma_f32_16x16x16f16(pk, w2f, dst[pp], 0, 0, 0);
        }
    };

    for (int jh = 0; jh < 8; ++jh) {         // 16 j-tiles, full 256-j sum in-wave
        dense_jt(jh * 2,     daccA);
        dense_jt(jh * 2 + 1, daccB);
    }

    // ---- masked residual update straight from registers ----
    // dacc D layout: row(4q+r) = x-pixel, col(l16) = channel
    #pragma unroll
    for (int pp = 0; pp < 2; ++pp) {
        const int y = y0 + pr + pp;
        #pragma unroll
        for (int r = 0; r < 4; ++r) {
            const int x = x0 + q * 4 + r;
            const size_t pixb = ((size_t)y * 64 + x) * 16;
            float sv = daccA[pp][r] + daccB[pp][r];
            float nv = gv[pp][r];
            if (a0v[pp][r] > 0.1f && l16 != 0) nv += sv + b2v;
            gob[pixb + l16] = nv;
        }
    }
}

// ---------------- final softmax over channels 1..10 ----------------
__global__ void softmax_out(const float* __restrict__ g, float* __restrict__ out) {
    int pix = blockIdx.x * 256 + threadIdx.x;
    if (pix >= NPIX) return;
    const float* gp = g + (size_t)pix * 16;
    float v[10];
    float m = -1e30f;
    #pragma unroll
    for (int i = 0; i < 10; ++i) { v[i] = gp[1 + i]; m = fmaxf(m, v[i]); }
    float s = 0.f;
    #pragma unroll
    for (int i = 0; i < 10; ++i) { v[i] = __expf(v[i] - m); s += v[i]; }
    float inv = 1.0f / s;
    float* op = out + (size_t)pix * 10;
    #pragma unroll
    for (int i = 0; i < 10; ++i) op[i] = v[i] * inv;
}

extern "C" void kernel_launch(void* const* d_in, const int* in_sizes, int n_in,
                              void* d_out, int out_size, void* d_ws, size_t ws_size,
                              hipStream_t stream) {
    const float* inp = (const float*)d_in[0];
    const float* cw  = (const float*)d_in[1];
    const float* cb  = (const float*)d_in[2];
    const float* w1  = (const float*)d_in[3];
    const float* b1  = (const float*)d_in[4];
    const float* w2  = (const float*)d_in[5];
    const float* b2  = (const float*)d_in[6];
    float* out = (float*)d_out;

    // grid double-buffer in d_ws (32 MB, proven)
    float* g0 = (float*)d_ws;
    float* g1 = g0 + GRID_ELEMS;
    // f16 weights in d_out scratch (115 KB of 10.48 MB; softmax overwrites at end)
    f16* wb = (f16*)d_out;

    prep_weights<<<224, 256, 0, stream>>>(cw, w1, w2, wb);
    init_grid<<<(GRID_ELEMS + 255) / 256, 256, 0, stream>>>(inp, g0);

    float* bufs[2] = { g0, g1 };
    for (int s = 0; s < NSTEP; ++s) {
        nca_step<<<2048, 256, 0, stream>>>(bufs[s & 1], bufs[(s + 1) & 1],
                                           wb, cb, b1, b2);
    }
    // NSTEP=60 even -> final state in g0
    softmax_out<<<(NPIX + 255) / 256, 256, 0, stream>>>(g0, out);
}